// Round 6
// baseline (590.891 us; speedup 1.0000x reference)
//
#include <hip/hip_runtime.h>
#include <hip/hip_bf16.h>

typedef unsigned short u16;
typedef unsigned int   u32;
typedef __attribute__((ext_vector_type(8))) short bf16x8;   // 8 bf16 = 4 VGPRs (MFMA A/B frag)
typedef __attribute__((ext_vector_type(4))) float f32x4;    // MFMA C/D frag

constexpr int B_    = 2;
constexpr int N_IN  = 50000;
constexpr int N_OUT = 12500;
constexpr int NNZ   = 500000;
constexpr int C     = 256;
constexpr int M_TOT = B_ * N_OUT;   // 25000 flattened rows of ax / out

constexpr int QB   = N_IN / 8;               // quant blocks: 4 waves x 4 records = 8 rows each
constexpr int NB_H = 128;                    // hist/scatter blocks (LDS-privatized)
constexpr int EPB  = (NNZ + NB_H - 1) / NB_H;   // 3907 edges per block

constexpr int REP  = 8;   // ROUND-12 AMPLIFICATION PROBE on the five small kernels.
                          // total = 326 + 7*Sum(S_small); top-5 monopolist = 8*S_max.

__device__ __forceinline__ u16 f2b(float f) {
    __hip_bfloat16 h = __float2bfloat16(f);
    return *(u16*)&h;
}

__device__ __forceinline__ u32 pack4(float4 f, float inv) {
    u32 u0 = (u32)(int)(rintf(f.x * inv) + 128.f);
    u32 u1 = (u32)(int)(rintf(f.y * inv) + 128.f);
    u32 u2 = (u32)(int)(rintf(f.z * inv) + 128.f);
    u32 u3 = (u32)(int)(rintf(f.w * inv) + 128.f);
    return u0 | (u1 << 8) | (u2 << 16) | (u3 << 24);
}

// ---------------- 1. x -> int8 quant (per-row,per-batch scale) --- PROBE x8 ----------------
__global__ __launch_bounds__(256) void quant_k(const float* __restrict__ x,
                                               u32* __restrict__ xq,
                                               float* __restrict__ xs) {
    int blk = blockIdx.x;
    int t   = threadIdx.x;
    int wv  = t >> 6, l = t & 63;
    int rec = l >> 4;                 // 0..3: record within wave
    int j   = l & 15;                 // lane within record (owns channels 16j..16j+15)
    int n   = blk * 8 + wv * 2 + (rec >> 1);
    int b   = rec & 1;
    const float4* px = (const float4*)(x + ((size_t)b * N_IN + n) * C + j * 16);
    for (int rep = 0; rep < REP; ++rep) {
        float4 f0 = px[0], f1 = px[1], f2 = px[2], f3 = px[3];
        float m0 = fmaxf(fmaxf(fabsf(f0.x), fabsf(f0.y)), fmaxf(fabsf(f0.z), fabsf(f0.w)));
        float m1 = fmaxf(fmaxf(fabsf(f1.x), fabsf(f1.y)), fmaxf(fabsf(f1.z), fabsf(f1.w)));
        float m2 = fmaxf(fmaxf(fabsf(f2.x), fabsf(f2.y)), fmaxf(fabsf(f2.z), fabsf(f2.w)));
        float m3 = fmaxf(fmaxf(fabsf(f3.x), fabsf(f3.y)), fmaxf(fabsf(f3.z), fabsf(f3.w)));
        float m  = fmaxf(fmaxf(m0, m1), fmaxf(m2, m3));
#pragma unroll
        for (int off = 1; off < 16; off <<= 1)
            m = fmaxf(m, __shfl_xor(m, off, 64));    // stays within 16-lane group
        float qstep = m * (1.f / 127.f);
        float inv   = 127.f / m;                     // x ~ N(0,1): m > 0 always
        if (j == 0) xs[n * 2 + b] = qstep;
        uint4 pk;
        pk.x = pack4(f0, inv);
        pk.y = pack4(f1, inv);
        pk.z = pack4(f2, inv);
        pk.w = pack4(f3, inv);
        *(uint4*)(xq + (size_t)n * 128 + b * 64 + j * 4) = pk;
        asm volatile("" ::: "memory");
    }
}

// ---------------- 1b. LDS-privatized row histogram --- PROBE x8 ----------------
__global__ __launch_bounds__(256) void hist_k(const int* __restrict__ rows,
                                              u16* __restrict__ partial) {
    __shared__ u32 lc[N_OUT];
    int t = threadIdx.x, blk = blockIdx.x;
    int base = blk * EPB;
    int end  = base + EPB < NNZ ? base + EPB : NNZ;
    for (int rep = 0; rep < REP; ++rep) {
        __syncthreads();                             // protect lc reuse across reps
        for (int i = t; i < N_OUT; i += 256) lc[i] = 0;
        __syncthreads();
        for (int i = base + t; i < end; i += 256)
            atomicAdd(&lc[rows[i]], 1u);             // LDS atomic: banked, cheap
        __syncthreads();
        for (int i = t; i < N_OUT; i += 256)
            partial[(size_t)blk * N_OUT + i] = (u16)lc[i];
        asm volatile("" ::: "memory");
    }
}

// ---------------- 1c. per-bin prefix over the 128 block-partials --- PROBE x8 ----------------
__global__ __launch_bounds__(256) void binprefix_k(const u16* __restrict__ partial,
                                                   u16* __restrict__ bp,
                                                   int* __restrict__ counts) {
    int bin = blockIdx.x * 256 + threadIdx.x;
    if (bin >= N_OUT) return;
    for (int rep = 0; rep < REP; ++rep) {
        u32 run = 0;
        for (int b = 0; b < NB_H; ++b) {
            u32 c = partial[(size_t)b * N_OUT + bin];
            bp[(size_t)b * N_OUT + bin] = (u16)run;
            run += c;
        }
        counts[bin] = (int)run;
        asm volatile("" ::: "memory");
    }
}

// ---------------- 2. fused scan + weight transpose --- PROBE x8 ----------------
constexpr int CHUNK = (N_OUT + 255) / 256;   // 49
__global__ __launch_bounds__(256) void scan_tw_k(const int* __restrict__ counts,
                                                 int* __restrict__ start,
                                                 const float* __restrict__ w,
                                                 u16* __restrict__ wt) {
    int tid = threadIdx.x;
    if (blockIdx.x > 0) {           // transpose: Wt[n][k] = W[k][n], bf16
        int n = blockIdx.x - 1;
        for (int rep = 0; rep < REP; ++rep) {
            wt[(size_t)n * C + tid] = f2b(w[(size_t)tid * C + n]);
            asm volatile("" ::: "memory");
        }
        return;
    }
    __shared__ int wsum[4];
    for (int rep = 0; rep < REP; ++rep) {
        __syncthreads();                             // protect wsum reuse across reps
        int base = tid * CHUNK;
        int s = 0;
        for (int j = 0; j < CHUNK; ++j) {
            int i = base + j;
            s += (i < N_OUT) ? counts[i] : 0;
        }
        int lane = tid & 63, wv = tid >> 6;
        int v = s;
#pragma unroll
        for (int off = 1; off < 64; off <<= 1) {
            int t2 = __shfl_up(v, off, 64);
            if (lane >= off) v += t2;
        }
        if (lane == 63) wsum[wv] = v;
        __syncthreads();
        int woff = 0;
        for (int ww = 0; ww < wv; ++ww) woff += wsum[ww];
        if (tid == 255) start[N_OUT] = woff + v;     // == NNZ
        int run = woff + v - s;                      // exclusive prefix of this chunk
        for (int j = 0; j < CHUNK; ++j) {
            int i = base + j;
            if (i < N_OUT) {
                start[i] = run;
                run += counts[i];
            }
        }
        asm volatile("" ::: "memory");
    }
}

// ---------------- 3. counting-sort scatter via LDS cursors --- PROBE x8 ----------------
__global__ __launch_bounds__(256) void scatter_k(const int* __restrict__ rows,
                                                 const int* __restrict__ cols,
                                                 const float* __restrict__ vals,
                                                 const int* __restrict__ start,
                                                 const u16* __restrict__ bp,
                                                 int2* __restrict__ edges) {
    __shared__ u32 lc[N_OUT];
    int t = threadIdx.x, blk = blockIdx.x;
    int base = blk * EPB;
    int end  = base + EPB < NNZ ? base + EPB : NNZ;
    for (int rep = 0; rep < REP; ++rep) {
        __syncthreads();                             // protect lc reuse across reps
        for (int i = t; i < N_OUT; i += 256)
            lc[i] = (u32)start[i] + (u32)bp[(size_t)blk * N_OUT + i];
        __syncthreads();
        for (int i = base + t; i < end; i += 256) {
            int r = rows[i];
            u32 p = atomicAdd(&lc[r], 1u);           // LDS atomic
            edges[p] = make_int2(cols[i], __float_as_int(vals[i]));
        }
        asm volatile("" ::: "memory");
    }
}

// ---------------- 4. SpMM on int8 x (clean round-2 version, proven in 326.0) ----------------
// lane: b = lane>>5, g = lane&31 -> channels g*8..g*8+7 of batch b.
// acc_j = sum vs*u ; true = acc_j - 128*sum(vs)  (u biased by +128)
__global__ __launch_bounds__(256) void spmm_q_k(const u32* __restrict__ xq,
                                                const float* __restrict__ xs,
                                                const int* __restrict__ start,
                                                const int2* __restrict__ edges,
                                                u32* __restrict__ ax) {
    int r    = blockIdx.x;
    int wv   = threadIdx.x >> 6;
    int lane = threadIdx.x & 63;
    int b    = lane >> 5;
    int g    = lane & 31;
    int loff = b * 64 + g * 2;        // u32 offset of this lane's 8 bytes within a row record

    int e0 = start[r], e1 = start[r + 1];
    float acc[8];
#pragma unroll
    for (int j = 0; j < 8; ++j) acc[j] = 0.f;
    float S = 0.f;

    auto body = [&](int2 d) {
        float vs = __int_as_float(d.y) * xs[d.x * 2 + b];
        uint2 q  = *(const uint2*)(xq + (size_t)d.x * 128 + loff);
        S += vs;
        acc[0] += vs * (float)( q.x        & 255u);
        acc[1] += vs * (float)((q.x >>  8) & 255u);
        acc[2] += vs * (float)((q.x >> 16) & 255u);
        acc[3] += vs * (float)( q.x >> 24        );
        acc[4] += vs * (float)( q.y        & 255u);
        acc[5] += vs * (float)((q.y >>  8) & 255u);
        acc[6] += vs * (float)((q.y >> 16) & 255u);
        acc[7] += vs * (float)( q.y >> 24        );
    };

    int e = e0 + wv;
    for (; e + 12 < e1; e += 16) {    // 4 edges in flight per wave
        int2 d0 = edges[e], d1 = edges[e + 4], d2 = edges[e + 8], d3 = edges[e + 12];
        body(d0); body(d1); body(d2); body(d3);
    }
    for (; e < e1; e += 4) body(edges[e]);

    __shared__ float red[4][64][8];
#pragma unroll
    for (int j = 0; j < 8; ++j) red[wv][lane][j] = acc[j] - 128.f * S;
    __syncthreads();
    if (wv == 0) {
        float4 lo = *(float4*)&red[0][lane][0];
        float4 hi = *(float4*)&red[0][lane][4];
#pragma unroll
        for (int ww = 1; ww < 4; ++ww) {
            float4 l2 = *(float4*)&red[ww][lane][0];
            float4 h2 = *(float4*)&red[ww][lane][4];
            lo.x += l2.x; lo.y += l2.y; lo.z += l2.z; lo.w += l2.w;
            hi.x += h2.x; hi.y += h2.y; hi.z += h2.z; hi.w += h2.w;
        }
        uint4 pk;
        pk.x = (u32)f2b(lo.x) | ((u32)f2b(lo.y) << 16);
        pk.y = (u32)f2b(lo.z) | ((u32)f2b(lo.w) << 16);
        pk.z = (u32)f2b(hi.x) | ((u32)f2b(hi.y) << 16);
        pk.w = (u32)f2b(hi.z) | ((u32)f2b(hi.w) << 16);
        u32* axrow = ax + ((size_t)b * N_OUT + r) * (C / 2);
        *(uint4*)(axrow + g * 4) = pk;
    }
}

// ---------------- 5. MFMA GEMM (clean round-2 version) ----------------
__global__ __launch_bounds__(256) void gemm_k(const u32* __restrict__ ax,
                                              const u16* __restrict__ wt,
                                              const float* __restrict__ bias,
                                              float* __restrict__ out) {
    int wave = threadIdx.x >> 6;
    int lane = threadIdx.x & 63;
    int quad = lane >> 4;
    int l15  = lane & 15;
    int m0   = blockIdx.x * 16;
    int n0   = wave * 64;

    int mrow = m0 + l15;
    int mr_c = mrow < M_TOT ? mrow : (M_TOT - 1);    // clamp; stores guarded below
    const u16* arow = (const u16*)(ax + (size_t)mr_c * (C / 2));

    f32x4 acc[4];
#pragma unroll
    for (int t = 0; t < 4; ++t) acc[t] = (f32x4){0.f, 0.f, 0.f, 0.f};

#pragma unroll
    for (int kt = 0; kt < 8; ++kt) {
        int k0 = kt * 32 + quad * 8;
        bf16x8 afrag = *(const bf16x8*)(arow + k0);   // A[m=l15][k=quad*8+j]
#pragma unroll
        for (int nt = 0; nt < 4; ++nt) {
            // B[k=quad*8+j][n=n0+nt*16+l15] -> Wt[n][k] contiguous in k
            bf16x8 bfrag = *(const bf16x8*)(wt + (size_t)(n0 + nt * 16 + l15) * C + k0);
            acc[nt] = __builtin_amdgcn_mfma_f32_16x16x32_bf16(afrag, bfrag, acc[nt], 0, 0, 0);
        }
    }

    // C/D layout: col = lane&15, row = quad*4 + reg   [measured m89/m91]
#pragma unroll
    for (int nt = 0; nt < 4; ++nt) {
        int col = n0 + nt * 16 + l15;
#pragma unroll
        for (int reg = 0; reg < 4; ++reg) {
            int rg = m0 + quad * 4 + reg;
            if (rg < M_TOT) {
                int rloc = (rg >= N_OUT) ? rg - N_OUT : rg;   // bias shared across batch
                out[(size_t)rg * C + col] = acc[nt][reg] + bias[(size_t)rloc * C + col];
            }
        }
    }
}

extern "C" void kernel_launch(void* const* d_in, const int* in_sizes, int n_in,
                              void* d_out, int out_size, void* d_ws, size_t ws_size,
                              hipStream_t stream) {
    const float* x      = (const float*)d_in[0];
    const int*   rows   = (const int*)d_in[1];
    const int*   cols   = (const int*)d_in[2];
    const float* vals   = (const float*)d_in[3];
    const float* weight = (const float*)d_in[4];
    const float* bias   = (const float*)d_in[5];
    float*       out    = (float*)d_out;

    char*  ws  = (char*)d_ws;
    size_t off = 0;
    auto alloc = [&](size_t bytes) -> void* {
        void* p = ws + off;
        off = (off + bytes + 255) & ~(size_t)255;
        return p;
    };
    int*   counts = (int*)  alloc((size_t)N_OUT * 4);
    int*   start  = (int*)  alloc((size_t)(N_OUT + 1) * 4);
    int2*  edges  = (int2*) alloc((size_t)NNZ * 8);
    u32*   ax     = (u32*)  alloc((size_t)M_TOT * (C / 2) * 4);   // bf16 packed
    u16*   wt     = (u16*)  alloc((size_t)C * C * 2);
    u32*   xq     = (u32*)  alloc((size_t)N_IN * 128 * 4);        // 25.6 MB int8 x
    float* xs     = (float*)alloc((size_t)N_IN * B_ * 4);         // per-(row,batch) qstep
    if (off > ws_size) return;  // ws too small -> leave output zeroed (visible failure)

    // partial/bp (3.2 MB each) alias onto ax: dead before spmm_q_k writes ax.
    u16* partial = (u16*)ax;
    u16* bp      = partial + (size_t)NB_H * N_OUT;

    quant_k    <<<QB, 256, 0, stream>>>(x, xq, xs);
    hist_k     <<<NB_H, 256, 0, stream>>>(rows, partial);
    binprefix_k<<<(N_OUT + 255) / 256, 256, 0, stream>>>(partial, bp, counts);
    scan_tw_k  <<<1 + C, 256, 0, stream>>>(counts, start, weight, wt);
    scatter_k  <<<NB_H, 256, 0, stream>>>(rows, cols, vals, start, bp, edges);
    spmm_q_k   <<<N_OUT, 256, 0, stream>>>(xq, xs, start, edges, ax);
    gemm_k     <<<(M_TOT + 15) / 16, 256, 0, stream>>>(ax, wt, bias, out);
}

// Round 7
// 308.076 us; speedup vs baseline: 1.9180x; 1.9180x over previous
//
#include <hip/hip_runtime.h>
#include <hip/hip_bf16.h>

typedef unsigned short u16;
typedef unsigned int   u32;
typedef __attribute__((ext_vector_type(8))) short bf16x8;   // 8 bf16 = 4 VGPRs (MFMA A/B frag)
typedef __attribute__((ext_vector_type(4))) float f32x4;    // MFMA C/D frag

constexpr int B_    = 2;
constexpr int N_IN  = 50000;
constexpr int N_OUT = 12500;
constexpr int NNZ   = 500000;
constexpr int C     = 256;
constexpr int M_TOT = B_ * N_OUT;   // 25000 flattened rows of ax / out

constexpr int QB     = N_IN / 8;             // quant blocks: 4 waves x 4 records = 8 rows each
constexpr int NB_H   = 128;                  // hist/scatter blocks (LDS-privatized)
constexpr int EPB    = (NNZ + NB_H - 1) / NB_H;   // 3907 edges per block
constexpr int NSLICE = (N_OUT + 255) / 256;  // 49 scan slices of 256 bins

__device__ __forceinline__ u16 f2b(float f) {
    __hip_bfloat16 h = __float2bfloat16(f);
    return *(u16*)&h;
}

__device__ __forceinline__ u32 pack4(float4 f, float inv) {
    u32 u0 = (u32)(int)(rintf(f.x * inv) + 128.f);
    u32 u1 = (u32)(int)(rintf(f.y * inv) + 128.f);
    u32 u2 = (u32)(int)(rintf(f.z * inv) + 128.f);
    u32 u3 = (u32)(int)(rintf(f.w * inv) + 128.f);
    return u0 | (u1 << 8) | (u2 << 16) | (u3 << 24);
}

// ---------------- 1. fused: x -> int8 quant  +  LDS-privatized row histogram ----------------
// Round-13: hist (S~4us) hides under quant's HBM stream (S~20us); -1 dispatch.
// LDS 50KB caps at 3 blocks/CU = 12 waves/CU resident: plenty for a pure-BW streamer.
__global__ __launch_bounds__(256) void quant_hist_k(const float* __restrict__ x,
                                                    u32* __restrict__ xq,
                                                    float* __restrict__ xs,
                                                    const int* __restrict__ rows,
                                                    u16* __restrict__ partial) {
    __shared__ u32 lc[N_OUT];      // used by hist blocks only (50 KB)
    int blk = blockIdx.x;
    int t   = threadIdx.x;
    if (blk < QB) {
        int wv  = t >> 6, l = t & 63;
        int rec = l >> 4;                 // 0..3: record within wave
        int j   = l & 15;                 // lane within record (owns channels 16j..16j+15)
        int n   = blk * 8 + wv * 2 + (rec >> 1);
        int b   = rec & 1;
        const float4* px = (const float4*)(x + ((size_t)b * N_IN + n) * C + j * 16);
        float4 f0 = px[0], f1 = px[1], f2 = px[2], f3 = px[3];
        float m0 = fmaxf(fmaxf(fabsf(f0.x), fabsf(f0.y)), fmaxf(fabsf(f0.z), fabsf(f0.w)));
        float m1 = fmaxf(fmaxf(fabsf(f1.x), fabsf(f1.y)), fmaxf(fabsf(f1.z), fabsf(f1.w)));
        float m2 = fmaxf(fmaxf(fabsf(f2.x), fabsf(f2.y)), fmaxf(fabsf(f2.z), fabsf(f2.w)));
        float m3 = fmaxf(fmaxf(fabsf(f3.x), fabsf(f3.y)), fmaxf(fabsf(f3.z), fabsf(f3.w)));
        float m  = fmaxf(fmaxf(m0, m1), fmaxf(m2, m3));
#pragma unroll
        for (int off = 1; off < 16; off <<= 1)
            m = fmaxf(m, __shfl_xor(m, off, 64));    // stays within 16-lane group
        float qstep = m * (1.f / 127.f);
        float inv   = 127.f / m;                     // x ~ N(0,1): m > 0 always
        if (j == 0) xs[n * 2 + b] = qstep;
        uint4 pk;
        pk.x = pack4(f0, inv);
        pk.y = pack4(f1, inv);
        pk.z = pack4(f2, inv);
        pk.w = pack4(f3, inv);
        *(uint4*)(xq + (size_t)n * 128 + b * 64 + j * 4) = pk;
    } else {
        int hb = blk - QB;
        for (int i = t; i < N_OUT; i += 256) lc[i] = 0;
        __syncthreads();
        int base = hb * EPB;
        int end  = base + EPB < NNZ ? base + EPB : NNZ;
        for (int i = base + t; i < end; i += 256)
            atomicAdd(&lc[rows[i]], 1u);             // LDS atomic: banked, cheap
        __syncthreads();
        for (int i = t; i < N_OUT; i += 256)
            partial[(size_t)hb * N_OUT + i] = (u16)lc[i];
    }
}

// ---------------- 2. per-bin prefix over 128 partials + block-local exclusive scan ----------
// Replaces binprefix_k + the 17us SERIAL single-block scan (round-6 probe: S_scan~17us,
// occupancy 0.2% -> latency-crawl). start[] is never materialized: consumers compute
// start[bin] = sliceoff[bin>>8] + startlocal[bin].
__global__ __launch_bounds__(256) void binpre2_k(const u16* __restrict__ partial,
                                                 u16* __restrict__ bp,
                                                 u32* __restrict__ startlocal,
                                                 int* __restrict__ slicesum) {
    int blk = blockIdx.x;                 // 0..NSLICE-1
    int bin = blk * 256 + threadIdx.x;
    u32 run = 0;
    if (bin < N_OUT) {
        for (int b = 0; b < NB_H; ++b) {
            u32 c = partial[(size_t)b * N_OUT + bin];
            bp[(size_t)b * N_OUT + bin] = (u16)run;
            run += c;
        }
    }
    // run == counts[bin] (0 for invalid bins); block-wide exclusive scan
    int lane = threadIdx.x & 63, wv = threadIdx.x >> 6;
    u32 v = run;
#pragma unroll
    for (int off = 1; off < 64; off <<= 1) {
        u32 t2 = __shfl_up(v, off, 64);
        if (lane >= off) v += t2;
    }
    __shared__ u32 wsum[4];
    if (lane == 63) wsum[wv] = v;
    __syncthreads();
    u32 woff = 0;
    for (int w = 0; w < wv; ++w) woff += wsum[w];
    u32 incl = woff + v;
    if (bin < N_OUT) startlocal[bin] = incl - run;       // exclusive prefix within slice
    if (threadIdx.x == 255) slicesum[blk] = (int)incl;   // slice total
}

// ---------------- 3. fused: 1-wave scan of slice sums (block 0) + weight transpose ----------
__global__ __launch_bounds__(256) void sliceoff_tw_k(const int* __restrict__ slicesum,
                                                     int* __restrict__ sliceoff,
                                                     const float* __restrict__ w,
                                                     u16* __restrict__ wt) {
    int tid = threadIdx.x;
    if (blockIdx.x > 0) {           // transpose: Wt[n][k] = W[k][n], bf16
        int n = blockIdx.x - 1;
        wt[(size_t)n * C + tid] = f2b(w[(size_t)tid * C + n]);
        return;
    }
    if (tid < 64) {
        int s = (tid < NSLICE) ? slicesum[tid] : 0;
        int v = s;
#pragma unroll
        for (int off = 1; off < 64; off <<= 1) {
            int t2 = __shfl_up(v, off, 64);
            if (tid >= off) v += t2;
        }
        if (tid < NSLICE) sliceoff[tid] = v - s;   // exclusive
    }
}

// ---------------- 4. counting-sort scatter via LDS cursors: ZERO global atomics ----------
__global__ __launch_bounds__(256) void scatter_k(const int* __restrict__ rows,
                                                 const int* __restrict__ cols,
                                                 const float* __restrict__ vals,
                                                 const int* __restrict__ sliceoff,
                                                 const u32* __restrict__ startlocal,
                                                 const u16* __restrict__ bp,
                                                 int2* __restrict__ edges) {
    __shared__ u32 lc[N_OUT];
    int t = threadIdx.x, blk = blockIdx.x;
    for (int i = t; i < N_OUT; i += 256)
        lc[i] = (u32)sliceoff[i >> 8] + startlocal[i] + (u32)bp[(size_t)blk * N_OUT + i];
    __syncthreads();
    int base = blk * EPB;
    int end  = base + EPB < NNZ ? base + EPB : NNZ;
    for (int i = base + t; i < end; i += 256) {
        int r = rows[i];
        u32 p = atomicAdd(&lc[r], 1u);           // LDS atomic
        edges[p] = make_int2(cols[i], __float_as_int(vals[i]));
    }
}

// ---------------- 5. SpMM on int8 x (round-2 structure, proven) ----------------
// lane: b = lane>>5, g = lane&31 -> channels g*8..g*8+7 of batch b.
// acc_j = sum vs*u ; true = acc_j - 128*sum(vs)  (u biased by +128)
__global__ __launch_bounds__(256) void spmm_q_k(const u32* __restrict__ xq,
                                                const float* __restrict__ xs,
                                                const int* __restrict__ sliceoff,
                                                const u32* __restrict__ startlocal,
                                                const int2* __restrict__ edges,
                                                u32* __restrict__ ax) {
    int r    = blockIdx.x;
    int wv   = threadIdx.x >> 6;
    int lane = threadIdx.x & 63;
    int b    = lane >> 5;
    int g    = lane & 31;
    int loff = b * 64 + g * 2;        // u32 offset of this lane's 8 bytes within a row record

    int e0 = sliceoff[r >> 8] + (int)startlocal[r];
    int e1 = (r == N_OUT - 1) ? NNZ : sliceoff[(r + 1) >> 8] + (int)startlocal[r + 1];

    float acc[8];
#pragma unroll
    for (int j = 0; j < 8; ++j) acc[j] = 0.f;
    float S = 0.f;

    auto body = [&](int2 d) {
        float vs = __int_as_float(d.y) * xs[d.x * 2 + b];
        uint2 q  = *(const uint2*)(xq + (size_t)d.x * 128 + loff);
        S += vs;
        acc[0] += vs * (float)( q.x        & 255u);
        acc[1] += vs * (float)((q.x >>  8) & 255u);
        acc[2] += vs * (float)((q.x >> 16) & 255u);
        acc[3] += vs * (float)( q.x >> 24        );
        acc[4] += vs * (float)( q.y        & 255u);
        acc[5] += vs * (float)((q.y >>  8) & 255u);
        acc[6] += vs * (float)((q.y >> 16) & 255u);
        acc[7] += vs * (float)( q.y >> 24        );
    };

    int e = e0 + wv;
    for (; e + 12 < e1; e += 16) {    // 4 edges in flight per wave
        int2 d0 = edges[e], d1 = edges[e + 4], d2 = edges[e + 8], d3 = edges[e + 12];
        body(d0); body(d1); body(d2); body(d3);
    }
    for (; e < e1; e += 4) body(edges[e]);

    __shared__ float red[4][64][8];
#pragma unroll
    for (int j = 0; j < 8; ++j) red[wv][lane][j] = acc[j] - 128.f * S;
    __syncthreads();
    if (wv == 0) {
        float4 lo = *(float4*)&red[0][lane][0];
        float4 hi = *(float4*)&red[0][lane][4];
#pragma unroll
        for (int ww = 1; ww < 4; ++ww) {
            float4 l2 = *(float4*)&red[ww][lane][0];
            float4 h2 = *(float4*)&red[ww][lane][4];
            lo.x += l2.x; lo.y += l2.y; lo.z += l2.z; lo.w += l2.w;
            hi.x += h2.x; hi.y += h2.y; hi.z += h2.z; hi.w += h2.w;
        }
        uint4 pk;
        pk.x = (u32)f2b(lo.x) | ((u32)f2b(lo.y) << 16);
        pk.y = (u32)f2b(lo.z) | ((u32)f2b(lo.w) << 16);
        pk.z = (u32)f2b(hi.x) | ((u32)f2b(hi.y) << 16);
        pk.w = (u32)f2b(hi.z) | ((u32)f2b(hi.w) << 16);
        u32* axrow = ax + ((size_t)b * N_OUT + r) * (C / 2);
        *(uint4*)(axrow + g * 4) = pk;
    }
}

// ---------------- 6. MFMA GEMM (round-2 version, measured ~launch-bound) ----------------
__global__ __launch_bounds__(256) void gemm_k(const u32* __restrict__ ax,
                                              const u16* __restrict__ wt,
                                              const float* __restrict__ bias,
                                              float* __restrict__ out) {
    int wave = threadIdx.x >> 6;
    int lane = threadIdx.x & 63;
    int quad = lane >> 4;
    int l15  = lane & 15;
    int m0   = blockIdx.x * 16;
    int n0   = wave * 64;

    int mrow = m0 + l15;
    int mr_c = mrow < M_TOT ? mrow : (M_TOT - 1);    // clamp; stores guarded below
    const u16* arow = (const u16*)(ax + (size_t)mr_c * (C / 2));

    f32x4 acc[4];
#pragma unroll
    for (int t = 0; t < 4; ++t) acc[t] = (f32x4){0.f, 0.f, 0.f, 0.f};

#pragma unroll
    for (int kt = 0; kt < 8; ++kt) {
        int k0 = kt * 32 + quad * 8;
        bf16x8 afrag = *(const bf16x8*)(arow + k0);   // A[m=l15][k=quad*8+j]
#pragma unroll
        for (int nt = 0; nt < 4; ++nt) {
            // B[k=quad*8+j][n=n0+nt*16+l15] -> Wt[n][k] contiguous in k
            bf16x8 bfrag = *(const bf16x8*)(wt + (size_t)(n0 + nt * 16 + l15) * C + k0);
            acc[nt] = __builtin_amdgcn_mfma_f32_16x16x32_bf16(afrag, bfrag, acc[nt], 0, 0, 0);
        }
    }

    // C/D layout: col = lane&15, row = quad*4 + reg   [measured m89/m91]
#pragma unroll
    for (int nt = 0; nt < 4; ++nt) {
        int col = n0 + nt * 16 + l15;
#pragma unroll
        for (int reg = 0; reg < 4; ++reg) {
            int rg = m0 + quad * 4 + reg;
            if (rg < M_TOT) {
                int rloc = (rg >= N_OUT) ? rg - N_OUT : rg;   // bias shared across batch
                out[(size_t)rg * C + col] = acc[nt][reg] + bias[(size_t)rloc * C + col];
            }
        }
    }
}

extern "C" void kernel_launch(void* const* d_in, const int* in_sizes, int n_in,
                              void* d_out, int out_size, void* d_ws, size_t ws_size,
                              hipStream_t stream) {
    const float* x      = (const float*)d_in[0];
    const int*   rows   = (const int*)d_in[1];
    const int*   cols   = (const int*)d_in[2];
    const float* vals   = (const float*)d_in[3];
    const float* weight = (const float*)d_in[4];
    const float* bias   = (const float*)d_in[5];
    float*       out    = (float*)d_out;

    char*  ws  = (char*)d_ws;
    size_t off = 0;
    auto alloc = [&](size_t bytes) -> void* {
        void* p = ws + off;
        off = (off + bytes + 255) & ~(size_t)255;
        return p;
    };
    u32*   startlocal = (u32*) alloc((size_t)N_OUT * 4);
    int*   slicesum   = (int*) alloc((size_t)NSLICE * 4);
    int*   sliceoff   = (int*) alloc((size_t)NSLICE * 4);
    int2*  edges      = (int2*)alloc((size_t)NNZ * 8);
    u32*   ax         = (u32*) alloc((size_t)M_TOT * (C / 2) * 4);   // bf16 packed
    u16*   wt         = (u16*) alloc((size_t)C * C * 2);
    u32*   xq         = (u32*) alloc((size_t)N_IN * 128 * 4);        // 25.6 MB int8 x
    float* xs         = (float*)alloc((size_t)N_IN * B_ * 4);        // per-(row,batch) qstep
    if (off > ws_size) return;  // ws too small -> leave output zeroed (visible failure)

    // partial/bp (3.2 MB each) alias onto ax: dead before spmm_q_k writes ax.
    u16* partial = (u16*)ax;
    u16* bp      = partial + (size_t)NB_H * N_OUT;

    quant_hist_k <<<QB + NB_H, 256, 0, stream>>>(x, xq, xs, rows, partial);
    binpre2_k    <<<NSLICE, 256, 0, stream>>>(partial, bp, startlocal, slicesum);
    sliceoff_tw_k<<<1 + C, 256, 0, stream>>>(slicesum, sliceoff, weight, wt);
    scatter_k    <<<NB_H, 256, 0, stream>>>(rows, cols, vals, sliceoff, startlocal, bp, edges);
    spmm_q_k     <<<N_OUT, 256, 0, stream>>>(xq, xs, sliceoff, startlocal, edges, ax);
    gemm_k       <<<(M_TOT + 15) / 16, 256, 0, stream>>>(ax, wt, bias, out);
}

// Round 8
// 303.174 us; speedup vs baseline: 1.9490x; 1.0162x over previous
//
#include <hip/hip_runtime.h>
#include <hip/hip_bf16.h>

typedef unsigned short u16;
typedef unsigned int   u32;
typedef __attribute__((ext_vector_type(8))) short bf16x8;   // 8 bf16 = 4 VGPRs (MFMA A/B frag)
typedef __attribute__((ext_vector_type(4))) float f32x4;    // MFMA C/D frag

constexpr int B_    = 2;
constexpr int N_IN  = 50000;
constexpr int N_OUT = 12500;
constexpr int NNZ   = 500000;
constexpr int C     = 256;
constexpr int M_TOT = B_ * N_OUT;   // 25000 flattened rows of ax / out

constexpr int QB     = N_IN / 8;             // quant blocks: 4 waves x 4 records = 8 rows each
constexpr int NB_H   = 128;                  // hist/scatter blocks (LDS-privatized)
constexpr int EPB    = (NNZ + NB_H - 1) / NB_H;   // 3907 edges per block
constexpr int NSLICE = (N_OUT + 255) / 256;  // 49 scan slices of 256 bins

__device__ __forceinline__ u16 f2b(float f) {
    __hip_bfloat16 h = __float2bfloat16(f);
    return *(u16*)&h;
}

__device__ __forceinline__ u32 pack4(float4 f, float inv) {
    u32 u0 = (u32)(int)(rintf(f.x * inv) + 128.f);
    u32 u1 = (u32)(int)(rintf(f.y * inv) + 128.f);
    u32 u2 = (u32)(int)(rintf(f.z * inv) + 128.f);
    u32 u3 = (u32)(int)(rintf(f.w * inv) + 128.f);
    return u0 | (u1 << 8) | (u2 << 16) | (u3 << 24);
}

// ---------------- 1. fused: quant + LDS-privatized hist + weight transpose ----------------
// Round-14: sliceoff_tw_k deleted; its transpose half lives here (+256 blocks), its scan
// half is recomputed in-block by scatter_k. 6 -> 5 dispatches.
__global__ __launch_bounds__(256) void quant_hist_tw_k(const float* __restrict__ x,
                                                       u32* __restrict__ xq,
                                                       float* __restrict__ xs,
                                                       const int* __restrict__ rows,
                                                       u16* __restrict__ partial,
                                                       const float* __restrict__ w,
                                                       u16* __restrict__ wt) {
    __shared__ u32 lc[N_OUT];      // used by hist blocks only (50 KB)
    int blk = blockIdx.x;
    int t   = threadIdx.x;
    if (blk < QB) {
        int wv  = t >> 6, l = t & 63;
        int rec = l >> 4;                 // 0..3: record within wave
        int j   = l & 15;                 // lane within record (owns channels 16j..16j+15)
        int n   = blk * 8 + wv * 2 + (rec >> 1);
        int b   = rec & 1;
        const float4* px = (const float4*)(x + ((size_t)b * N_IN + n) * C + j * 16);
        float4 f0 = px[0], f1 = px[1], f2 = px[2], f3 = px[3];
        float m0 = fmaxf(fmaxf(fabsf(f0.x), fabsf(f0.y)), fmaxf(fabsf(f0.z), fabsf(f0.w)));
        float m1 = fmaxf(fmaxf(fabsf(f1.x), fabsf(f1.y)), fmaxf(fabsf(f1.z), fabsf(f1.w)));
        float m2 = fmaxf(fmaxf(fabsf(f2.x), fabsf(f2.y)), fmaxf(fabsf(f2.z), fabsf(f2.w)));
        float m3 = fmaxf(fmaxf(fabsf(f3.x), fabsf(f3.y)), fmaxf(fabsf(f3.z), fabsf(f3.w)));
        float m  = fmaxf(fmaxf(m0, m1), fmaxf(m2, m3));
#pragma unroll
        for (int off = 1; off < 16; off <<= 1)
            m = fmaxf(m, __shfl_xor(m, off, 64));    // stays within 16-lane group
        float qstep = m * (1.f / 127.f);
        float inv   = 127.f / m;                     // x ~ N(0,1): m > 0 always
        if (j == 0) xs[n * 2 + b] = qstep;
        uint4 pk;
        pk.x = pack4(f0, inv);
        pk.y = pack4(f1, inv);
        pk.z = pack4(f2, inv);
        pk.w = pack4(f3, inv);
        *(uint4*)(xq + (size_t)n * 128 + b * 64 + j * 4) = pk;
    } else if (blk < QB + NB_H) {
        int hb = blk - QB;
        for (int i = t; i < N_OUT; i += 256) lc[i] = 0;
        __syncthreads();
        int base = hb * EPB;
        int end  = base + EPB < NNZ ? base + EPB : NNZ;
        for (int i = base + t; i < end; i += 256)
            atomicAdd(&lc[rows[i]], 1u);             // LDS atomic: banked, cheap
        __syncthreads();
        for (int i = t; i < N_OUT; i += 256)
            partial[(size_t)hb * N_OUT + i] = (u16)lc[i];
    } else {                        // transpose: Wt[n][k] = W[k][n], bf16
        int n = blk - QB - NB_H;
        wt[(size_t)n * C + t] = f2b(w[(size_t)t * C + n]);
    }
}

// ---------------- 2. per-bin prefix over 128 partials + block-local exclusive scan ----------
__global__ __launch_bounds__(256) void binpre2_k(const u16* __restrict__ partial,
                                                 u16* __restrict__ bp,
                                                 u32* __restrict__ startlocal,
                                                 int* __restrict__ slicesum) {
    int blk = blockIdx.x;                 // 0..NSLICE-1
    int bin = blk * 256 + threadIdx.x;
    u32 run = 0;
    if (bin < N_OUT) {
        for (int b = 0; b < NB_H; ++b) {
            u32 c = partial[(size_t)b * N_OUT + bin];
            bp[(size_t)b * N_OUT + bin] = (u16)run;
            run += c;
        }
    }
    // run == counts[bin] (0 for invalid bins); block-wide exclusive scan
    int lane = threadIdx.x & 63, wv = threadIdx.x >> 6;
    u32 v = run;
#pragma unroll
    for (int off = 1; off < 64; off <<= 1) {
        u32 t2 = __shfl_up(v, off, 64);
        if (lane >= off) v += t2;
    }
    __shared__ u32 wsum[4];
    if (lane == 63) wsum[wv] = v;
    __syncthreads();
    u32 woff = 0;
    for (int w = 0; w < wv; ++w) woff += wsum[w];
    u32 incl = woff + v;
    if (bin < N_OUT) startlocal[bin] = incl - run;       // exclusive prefix within slice
    if (threadIdx.x == 255) slicesum[blk] = (int)incl;   // slice total
}

// ---------------- 3. scatter via LDS cursors; in-block slice scan; blk0 writes start[] ------
__global__ __launch_bounds__(256) void scatter_k(const int* __restrict__ rows,
                                                 const int* __restrict__ cols,
                                                 const float* __restrict__ vals,
                                                 const int* __restrict__ slicesum,
                                                 const u32* __restrict__ startlocal,
                                                 const u16* __restrict__ bp,
                                                 int2* __restrict__ edges,
                                                 int* __restrict__ start) {
    __shared__ u32 lc[N_OUT];
    __shared__ int soff[64];
    int t = threadIdx.x, blk = blockIdx.x;
    if (t < 64) {                    // 1-wave exclusive scan of the 49 slice sums
        int s = (t < NSLICE) ? slicesum[t] : 0;
        int v = s;
#pragma unroll
        for (int off = 1; off < 64; off <<= 1) {
            int t2 = __shfl_up(v, off, 64);
            if (t >= off) v += t2;
        }
        soff[t] = v - s;
    }
    __syncthreads();
    for (int i = t; i < N_OUT; i += 256) {
        u32 st = (u32)soff[i >> 8] + startlocal[i];
        lc[i] = st + (u32)bp[(size_t)blk * N_OUT + i];
        if (blk == 0) start[i] = (int)st;    // materialize start[] for spmm
    }
    if (blk == 0 && t == 0) start[N_OUT] = NNZ;
    __syncthreads();
    int base = blk * EPB;
    int end  = base + EPB < NNZ ? base + EPB : NNZ;
    for (int i = base + t; i < end; i += 256) {
        int r = rows[i];
        u32 p = atomicAdd(&lc[r], 1u);           // LDS atomic
        edges[p] = make_int2(cols[i], __float_as_int(vals[i]));
    }
}

// ---------------- 4. SpMM on int8 x — uint4 gather, 2 edges per wave ----------------
// Round-14: each edge gathered as 32 lanes x 16B (was 64 x 8B) -> half the L2 requests.
// lane: h = lane>>5 (edge of the pair), g2 = lane&31 -> batch b=g2>>4, channels
// (g2&15)*16 .. +15. Halves folded via shfl_xor(32); epilogue preserves the original
// lane->channel output mapping. 4 records in flight per wave (proven depth).
__global__ __launch_bounds__(256) void spmm_q_k(const u32* __restrict__ xq,
                                                const float* __restrict__ xs,
                                                const int* __restrict__ start,
                                                const int2* __restrict__ edges,
                                                u32* __restrict__ ax) {
    int r    = blockIdx.x;
    int wv   = threadIdx.x >> 6;
    int lane = threadIdx.x & 63;
    int h    = lane >> 5;
    int g2   = lane & 31;
    int b    = g2 >> 4;

    int e0 = start[r], e1 = start[r + 1];

    float acc[16];
#pragma unroll
    for (int j = 0; j < 16; ++j) acc[j] = 0.f;
    float S = 0.f;

    auto body = [&](int2 d) {
        float vs = __int_as_float(d.y) * xs[d.x * 2 + b];
        uint4 q  = *(const uint4*)(xq + (size_t)d.x * 128 + g2 * 4);
        S += vs;
        acc[ 0] += vs * (float)( q.x        & 255u);
        acc[ 1] += vs * (float)((q.x >>  8) & 255u);
        acc[ 2] += vs * (float)((q.x >> 16) & 255u);
        acc[ 3] += vs * (float)( q.x >> 24        );
        acc[ 4] += vs * (float)( q.y        & 255u);
        acc[ 5] += vs * (float)((q.y >>  8) & 255u);
        acc[ 6] += vs * (float)((q.y >> 16) & 255u);
        acc[ 7] += vs * (float)( q.y >> 24        );
        acc[ 8] += vs * (float)( q.z        & 255u);
        acc[ 9] += vs * (float)((q.z >>  8) & 255u);
        acc[10] += vs * (float)((q.z >> 16) & 255u);
        acc[11] += vs * (float)( q.z >> 24        );
        acc[12] += vs * (float)( q.w        & 255u);
        acc[13] += vs * (float)((q.w >>  8) & 255u);
        acc[14] += vs * (float)((q.w >> 16) & 255u);
        acc[15] += vs * (float)( q.w >> 24        );
    };

    int e = e0 + wv * 2 + h;                   // 8 edge-streams per block (4 waves x 2)
    for (; e + 8 < e1; e += 16) {              // 2 in flight per half = 4 per wave
        int2 d0 = edges[e], d1 = edges[e + 8];
        body(d0); body(d1);
    }
    for (; e < e1; e += 8) body(edges[e]);

    // fold the two halves: lane l <-> l^32 share (b, g2)
#pragma unroll
    for (int j = 0; j < 16; ++j) acc[j] += __shfl_xor(acc[j], 32, 64);
    S += __shfl_xor(S, 32, 64);

    __shared__ float red[4][32][20];           // stride 20: 16B-aligned float4 rows
    if (h == 0) {
#pragma unroll
        for (int j = 0; j < 16; ++j) red[wv][g2][j] = acc[j] - 128.f * S;
    }
    __syncthreads();
    if (wv == 0) {
        // original output mapping: lane l -> b=l>>5, g=l&31, channels g*8..g*8+7
        int bb  = lane >> 5, g = lane & 31;
        int idx = bb * 16 + (g >> 1);          // source 16-ch group
        int j0  = (g & 1) * 8;                 // offset within the group
        float o[8];
#pragma unroll
        for (int i = 0; i < 8; ++i) o[i] = 0.f;
#pragma unroll
        for (int w = 0; w < 4; ++w) {
            float4 lo = *(float4*)&red[w][idx][j0];
            float4 hi = *(float4*)&red[w][idx][j0 + 4];
            o[0] += lo.x; o[1] += lo.y; o[2] += lo.z; o[3] += lo.w;
            o[4] += hi.x; o[5] += hi.y; o[6] += hi.z; o[7] += hi.w;
        }
        uint4 pk;
        pk.x = (u32)f2b(o[0]) | ((u32)f2b(o[1]) << 16);
        pk.y = (u32)f2b(o[2]) | ((u32)f2b(o[3]) << 16);
        pk.z = (u32)f2b(o[4]) | ((u32)f2b(o[5]) << 16);
        pk.w = (u32)f2b(o[6]) | ((u32)f2b(o[7]) << 16);
        u32* axrow = ax + ((size_t)bb * N_OUT + r) * (C / 2);
        *(uint4*)(axrow + g * 4) = pk;
    }
}

// ---------------- 5. MFMA GEMM (round-2 version, measured ~launch-bound) ----------------
__global__ __launch_bounds__(256) void gemm_k(const u32* __restrict__ ax,
                                              const u16* __restrict__ wt,
                                              const float* __restrict__ bias,
                                              float* __restrict__ out) {
    int wave = threadIdx.x >> 6;
    int lane = threadIdx.x & 63;
    int quad = lane >> 4;
    int l15  = lane & 15;
    int m0   = blockIdx.x * 16;
    int n0   = wave * 64;

    int mrow = m0 + l15;
    int mr_c = mrow < M_TOT ? mrow : (M_TOT - 1);    // clamp; stores guarded below
    const u16* arow = (const u16*)(ax + (size_t)mr_c * (C / 2));

    f32x4 acc[4];
#pragma unroll
    for (int t = 0; t < 4; ++t) acc[t] = (f32x4){0.f, 0.f, 0.f, 0.f};

#pragma unroll
    for (int kt = 0; kt < 8; ++kt) {
        int k0 = kt * 32 + quad * 8;
        bf16x8 afrag = *(const bf16x8*)(arow + k0);   // A[m=l15][k=quad*8+j]
#pragma unroll
        for (int nt = 0; nt < 4; ++nt) {
            // B[k=quad*8+j][n=n0+nt*16+l15] -> Wt[n][k] contiguous in k
            bf16x8 bfrag = *(const bf16x8*)(wt + (size_t)(n0 + nt * 16 + l15) * C + k0);
            acc[nt] = __builtin_amdgcn_mfma_f32_16x16x32_bf16(afrag, bfrag, acc[nt], 0, 0, 0);
        }
    }

    // C/D layout: col = lane&15, row = quad*4 + reg   [measured m89/m91]
#pragma unroll
    for (int nt = 0; nt < 4; ++nt) {
        int col = n0 + nt * 16 + l15;
#pragma unroll
        for (int reg = 0; reg < 4; ++reg) {
            int rg = m0 + quad * 4 + reg;
            if (rg < M_TOT) {
                int rloc = (rg >= N_OUT) ? rg - N_OUT : rg;   // bias shared across batch
                out[(size_t)rg * C + col] = acc[nt][reg] + bias[(size_t)rloc * C + col];
            }
        }
    }
}

extern "C" void kernel_launch(void* const* d_in, const int* in_sizes, int n_in,
                              void* d_out, int out_size, void* d_ws, size_t ws_size,
                              hipStream_t stream) {
    const float* x      = (const float*)d_in[0];
    const int*   rows   = (const int*)d_in[1];
    const int*   cols   = (const int*)d_in[2];
    const float* vals   = (const float*)d_in[3];
    const float* weight = (const float*)d_in[4];
    const float* bias   = (const float*)d_in[5];
    float*       out    = (float*)d_out;

    char*  ws  = (char*)d_ws;
    size_t off = 0;
    auto alloc = [&](size_t bytes) -> void* {
        void* p = ws + off;
        off = (off + bytes + 255) & ~(size_t)255;
        return p;
    };
    u32*   startlocal = (u32*) alloc((size_t)N_OUT * 4);
    int*   slicesum   = (int*) alloc((size_t)NSLICE * 4);
    int*   start      = (int*) alloc((size_t)(N_OUT + 1) * 4);
    int2*  edges      = (int2*)alloc((size_t)NNZ * 8);
    u32*   ax         = (u32*) alloc((size_t)M_TOT * (C / 2) * 4);   // bf16 packed
    u16*   wt         = (u16*) alloc((size_t)C * C * 2);
    u32*   xq         = (u32*) alloc((size_t)N_IN * 128 * 4);        // 25.6 MB int8 x
    float* xs         = (float*)alloc((size_t)N_IN * B_ * 4);        // per-(row,batch) qstep
    if (off > ws_size) return;  // ws too small -> leave output zeroed (visible failure)

    // partial/bp (3.2 MB each) alias onto ax: dead before spmm_q_k writes ax.
    u16* partial = (u16*)ax;
    u16* bp      = partial + (size_t)NB_H * N_OUT;

    quant_hist_tw_k<<<QB + NB_H + C, 256, 0, stream>>>(x, xq, xs, rows, partial, weight, wt);
    binpre2_k      <<<NSLICE, 256, 0, stream>>>(partial, bp, startlocal, slicesum);
    scatter_k      <<<NB_H, 256, 0, stream>>>(rows, cols, vals, slicesum, startlocal, bp,
                                              edges, start);
    spmm_q_k       <<<N_OUT, 256, 0, stream>>>(xq, xs, start, edges, ax);
    gemm_k         <<<(M_TOT + 15) / 16, 256, 0, stream>>>(ax, wt, bias, out);
}